// Round 1
// 817.328 us; speedup vs baseline: 1.0109x; 1.0109x over previous
//
#include <hip/hip_runtime.h>

typedef __bf16 bf16x8 __attribute__((ext_vector_type(8)));
typedef float f32x4 __attribute__((ext_vector_type(4)));

namespace {

constexpr int T_ = 64;
constexpr int N_ = 300;
constexpr int MD_ = 32;
constexpr int BG_ = 8;                        // B*G
constexpr long MROWS_ = (long)BG_ * T_ * N_;  // 153600
constexpr long FUSED_N = MROWS_ * 256;        // 39321600
constexpr int MB = 64;                        // rows per block (main kernel)

// packed-weight offsets in bf16 elements inside d_ws (after 256-byte header)
constexpr long PA1 = 0;        // adp_w1 [256][1024]
constexpr long PA2 = 262144;   // adp_w2 [1024][256]
constexpr long PF1 = 524288;   // fus_w1 [288][256]
constexpr long PF2 = 598016;   // fus_w2 [256][256]
constexpr long PN1 = 663552;   // ffn_w1 [256][1024]
constexpr long PN2 = 925696;   // ffn_w2 [1024][256]

// fast tanh-form GELU: |delta| vs erf-GELU <= ~2e-3 (under bf16 noise)
__device__ __forceinline__ float gelu_f(float x) {
  const float x2 = x * x;
  const float z2 = x * fmaf(x2, 0.07135481627f, 1.5957691216f);  // 2*z
  const float t = __builtin_amdgcn_rcpf(1.0f + __expf(z2));      // (1-tanh z)/2
  return x * (1.0f - t);
}

__device__ __forceinline__ float gelu_exact(float x) {
  return 0.5f * x * (1.0f + erff(x * 0.7071067811865476f));
}

// async global->LDS DMA, 16B per lane; LDS dst = wave-uniform base + lane*16
__device__ __forceinline__ void glds16(const void* g, void* l) {
  __builtin_amdgcn_global_load_lds(
      (const __attribute__((address_space(1))) void*)g,
      (__attribute__((address_space(3))) void*)l, 16, 0, 0);
}

// ---------------- mask dtype detection ----------------
__global__ void k_zero_flag(int* f) { *f = 0; }

__global__ void k_detect_mask(const unsigned char* __restrict__ m, int nbytes,
                              int* __restrict__ f) {
  int i = blockIdx.x * 256 + threadIdx.x;
  if (i < nbytes && (i & 3) != 0 && m[i] != 0) atomicOr(f, 1);
}

// ---------------- motion features (unchanged, verified) ----------------
__global__ __launch_bounds__(256)
void k_motion(const float* __restrict__ boxes, const void* __restrict__ masks,
              const int* __restrict__ times,
              const float* __restrict__ mw1, const float* __restrict__ mb1,
              const float* __restrict__ mw2, const float* __restrict__ mb2,
              float* __restrict__ motion, const int* __restrict__ flagp) {
  __shared__ int slot[4][T_];
  __shared__ int sts[4][T_];
  __shared__ float sbx[4][T_][4];
  __shared__ float otile[4][T_][MD_];
  const int tid = threadIdx.x;
  const int w = tid >> 6, l = tid & 63;
  const int traj = blockIdx.x * 4 + w;
  const int bg = traj / N_, n = traj - bg * N_;
  const int isbool = *flagp;
  const long idx = ((long)bg * T_ + l) * N_ + n;  // t = l
  const bool msk = isbool ? (((const unsigned char*)masks)[idx] != 0)
                          : (((const int*)masks)[idx] != 0);
  const bool valid = !msk;
  const int tm = times[idx];

  slot[w][l] = -1;
  sts[w][l] = 0;
  *(float4*)&sbx[w][l][0] = make_float4(0.f, 0.f, 0.f, 0.f);
  __syncthreads();
  if (valid) slot[w][tm] = l;
  __syncthreads();

  const int ot = slot[w][l];
  const bool vp = ot >= 0;
  const unsigned long long bal = __ballot(vp);
  const int cnt = __builtin_popcountll(bal);
  const int pos = __builtin_popcountll(bal & ((1ull << l) - 1ull));
  if (vp) {
    sts[w][pos] = l;
    const float4 bx = *(const float4*)(boxes + (((long)bg * T_ + ot) * N_ + n) * 4);
    *(float4*)&sbx[w][pos][0] = bx;
  }
  __syncthreads();

  const int stp = sts[w][l];
  const int stm1 = sts[w][(l + 63) & 63];
  const float4 sb = *(const float4*)&sbx[w][l][0];
  const float4 sbm = *(const float4*)&sbx[w][(l + 63) & 63][0];
  const float dt = (float)max(stp - stm1, 1);
  const float inv = 1.0f / dt;
  const bool okv = (l >= 1) && (l < cnt);
  float v0 = okv ? (sb.x - sbm.x) * inv : 0.f;
  float v1 = okv ? (sb.y - sbm.y) * inv : 0.f;
  float v2 = okv ? (sb.z - sbm.z) * inv : 0.f;
  float v3 = okv ? (sb.w - sbm.w) * inv : 0.f;
  const float p0 = __shfl_up(v0, 1, 64);
  const float p1 = __shfl_up(v1, 1, 64);
  const float p2 = __shfl_up(v2, 1, 64);
  const float p3 = __shfl_up(v3, 1, 64);
  const bool oka = (l >= 2) && (l < cnt);
  const float a0 = oka ? (v0 - p0) * inv : 0.f;
  const float a1 = oka ? (v1 - p1) * inv : 0.f;
  const float a2 = oka ? (v2 - p2) * inv : 0.f;
  const float a3 = oka ? (v3 - p3) * inv : 0.f;

  const float mv[12] = {sb.x, sb.y, sb.z, sb.w, v0, v1, v2, v3, a0, a1, a2, a3};
  float e1[16];
#pragma unroll
  for (int i = 0; i < 16; ++i) {
    float a = mb1[i];
#pragma unroll
    for (int c = 0; c < 12; ++c) a = fmaf(mv[c], mw1[c * 16 + i], a);
    e1[i] = gelu_exact(a);
  }
  float enc[32];
#pragma unroll
  for (int o = 0; o < 32; ++o) {
    float a = mb2[o];
#pragma unroll
    for (int i = 0; i < 16; ++i) a = fmaf(e1[i], mw2[i * 32 + o], a);
    enc[o] = a;
  }

#pragma unroll
  for (int c = 0; c < 32; c += 4)
    *(float4*)&otile[w][l][c] = make_float4(0.f, 0.f, 0.f, 0.f);
  __syncthreads();
  if (l < cnt && cnt >= 2) {
#pragma unroll
    for (int c = 0; c < 32; ++c) otile[w][stp][c] = enc[c];
  }
  __syncthreads();

  float* mbase = motion + ((long)bg * T_ * N_ + n) * MD_;
  const float4* srcv = (const float4*)&otile[w][l][0];
  float4* dstv = (float4*)(mbase + (long)l * N_ * MD_);
#pragma unroll
  for (int q = 0; q < 8; ++q) dstv[q] = srcv[q];
}

// ---------------- weight packing: f32 row-major -> bf16 MFMA-B fragments ----
// frag f = kb*(NN/16)+nt holds B[kb*32 + (l>>4)*8 + e][nt*16 + (l&15)],
// stored lane-contiguous: P[(f*64 + l)*8 + e]
__global__ void k_pack(const float* __restrict__ W, __bf16* __restrict__ P,
                       int K, int NN) {
  int gid = blockIdx.x * 256 + threadIdx.x;
  int total = (K >> 5) * (NN >> 4) * 64;
  if (gid >= total) return;
  int l = gid & 63, f = gid >> 6;
  int NT = NN >> 4;
  int kb = f / NT, nt = f - kb * NT;
  int krow = kb * 32 + (l >> 4) * 8;
  int col = nt * 16 + (l & 15);
  bf16x8 v;
#pragma unroll
  for (int e = 0; e < 8; ++e) v[e] = (__bf16)W[(long)(krow + e) * NN + col];
  *(bf16x8*)(P + (long)gid * 8) = v;
}

// ---------------- fused MFMA row pipeline ----------------
// R10 structure: counted-vmcnt deep pipeline (T3+T4 port).
// Weight ring is now 4 x 16KB slabs (one kb=32 K-slice each); mmG runs 8
// steps with 2-step DMA lookahead and NEVER drains vmcnt to 0 in steady
// state: per step {stage(kb+2); s_waitcnt vmcnt(4); s_barrier; 8 MFMA}.
// All inter-phase __syncthreads (which drain vmcnt and would kill the
// in-flight prefetch) are replaced by lgkmcnt(0)-only raw barriers, and
// each GEMM's first two slabs are prestaged during the preceding
// epilogue (store_gelu / LN / motion staging) so pipeline fill latency
// hides under VALU work. Hazards: every slab write is >=1 barrier after
// its last cross-wave read (8 in-loop barriers/mmG); vmcnt retirement is
// in-order and slab kb always has >=4 younger loads, so vmcnt(4) retires
// it regardless of stray bias/motion loads in the queue.
__global__ __launch_bounds__(512, 1)
void k_mfma(const float* __restrict__ feats, const float* __restrict__ motion,
            const __bf16* __restrict__ pw,
            const float* __restrict__ ba1, const float* __restrict__ ba2,
            const float* __restrict__ ng, const float* __restrict__ nb,
            const float* __restrict__ bf1, const float* __restrict__ bf2,
            const float* __restrict__ bn1, const float* __restrict__ bn2,
            const float* __restrict__ fg, const float* __restrict__ fb,
            float* __restrict__ out) {
  __shared__ __align__(16) char smem[131072];
  __shared__ float red[MB][4][2];  // per-row cross-wn LN partials
  char* regA = smem;               // [64][256] bf16 swizzled: x / LN1 / f
  char* regB = smem + 32768;       // [64][256] bf16 swizzled: h-chunk / g1
  char* regM = regB;               // motion tile aliases regB[0..4096)
  char* Bbuf = smem + 65536;       // 4 x 16KB weight slab ring

  const int tid = threadIdx.x;
  const int l = tid & 63, wid = tid >> 6;
  const int lr = l & 15, lk = l >> 4;
  const int wm = wid >> 2;    // 0..1 : row half (32 rows)
  const int wn = wid & 3;     // 0..3 : 64-col slice within 256-chunk
  const int colb = wn * 64;
  const long rowbase = (long)blockIdx.x * MB;

  const __bf16* pa1 = pw + PA1;
  const __bf16* pa2 = pw + PA2;
  const __bf16* pf1 = pw + PF1;
  const __bf16* pf2 = pw + PF2;
  const __bf16* pn1 = pw + PN1;
  const __bf16* pn2 = pw + PN2;

  auto lda = [&](const char* reg, int kb, int m) -> bf16x8 {
    const int row = wm * 32 + m * 16 + lr;
    return *(const bf16x8*)(reg + row * 512 +
                            ((((kb << 2) + lk) ^ (row & 7)) << 4));
  };
  auto ldb = [&](const __bf16* pb, int frag) -> bf16x8 {  // direct global
    return *(const bf16x8*)(pb + ((long)frag << 9) + (l << 3));
  };
  // stage one kb-slab (16 frags = 16KB) into ring slot via 2 async DMA
  auto stage1 = [&](const __bf16* pb, long fragbase, int NT, int kb, int slot) {
    const char* s = (const char*)pb + ((fragbase + (long)kb * NT) << 10);
    char* d = Bbuf + (slot << 14);
    const int o = tid << 4;
    glds16(s + o, d + o);
    glds16(s + 8192 + o, d + 8192 + o);
  };
  // issue the first two slabs of an upcoming mmG (pipeline fill)
  auto prestage = [&](const __bf16* pb, long fragbase, int NT) {
    stage1(pb, fragbase, NT, 0, 0);
    stage1(pb, fragbase, NT, 1, 1);
  };
  // LDS-visible workgroup barrier that leaves VMEM (DMA prefetch) in flight
  auto barrier_lds = [&]() {
    asm volatile("s_waitcnt lgkmcnt(0)" ::: "memory");
    __builtin_amdgcn_s_barrier();
    __builtin_amdgcn_sched_barrier(0);
  };
  // pipelined K=256 chunk GEMM: 8 kb-steps, 2-step lookahead, counted vmcnt.
  // PRECONDITION: prestage(pb, fragbase, NT) already issued.
  auto mmG = [&](const char* reg, const __bf16* pb, long fragbase, int NT,
                 f32x4 (&acc)[2][4]) {
#pragma unroll
    for (int kb = 0; kb < 8; ++kb) {
      if (kb < 6) {
        stage1(pb, fragbase, NT, kb + 2, (kb + 2) & 3);
        asm volatile("s_waitcnt vmcnt(4)" ::: "memory");  // slab kb landed
      } else if (kb == 6) {
        asm volatile("s_waitcnt vmcnt(2)" ::: "memory");
      } else {
        asm volatile("s_waitcnt vmcnt(0)" ::: "memory");
      }
      __builtin_amdgcn_s_barrier();
      __builtin_amdgcn_sched_barrier(0);
      __builtin_amdgcn_s_setprio(1);
      const bf16x8 a0 = lda(reg, kb, 0);
      const bf16x8 a1 = lda(reg, kb, 1);
      const char* buf = Bbuf + ((kb & 3) << 14);
#pragma unroll
      for (int j = 0; j < 4; ++j) {
        const bf16x8 b =
            *(const bf16x8*)(buf + ((wn * 4 + j) << 10) + (l << 4));
        acc[0][j] =
            __builtin_amdgcn_mfma_f32_16x16x32_bf16(a0, b, acc[0][j], 0, 0, 0);
        acc[1][j] =
            __builtin_amdgcn_mfma_f32_16x16x32_bf16(a1, b, acc[1][j], 0, 0, 0);
      }
      __builtin_amdgcn_s_setprio(0);
    }
  };
  // store gelu(acc) as bf16 into swizzled [64][256] tile
  auto store_gelu = [&](char* reg, const f32x4 (&acc)[2][4]) {
#pragma unroll
    for (int j = 0; j < 4; ++j) {
      const int col = colb + j * 16 + lr;
#pragma unroll
      for (int m = 0; m < 2; ++m)
#pragma unroll
        for (int e = 0; e < 4; ++e) {
          const int row = wm * 32 + m * 16 + lk * 4 + e;
          *(__bf16*)(reg + row * 512 + (((col >> 3) ^ (row & 7)) << 4) +
                     ((col & 7) << 1)) = (__bf16)gelu_f(acc[m][j][e]);
        }
    }
  };
  // fragment-layout LN stats: mean/rstd per owned row (m,e)
  auto ln_stats = [&](const f32x4 (&acc)[2][4], float (&mean)[2][4],
                      float (&rstd)[2][4]) {
    float s1[2][4], s2[2][4];
#pragma unroll
    for (int m = 0; m < 2; ++m)
#pragma unroll
      for (int e = 0; e < 4; ++e) { s1[m][e] = 0.f; s2[m][e] = 0.f; }
#pragma unroll
    for (int m = 0; m < 2; ++m)
#pragma unroll
      for (int j = 0; j < 4; ++j)
#pragma unroll
        for (int e = 0; e < 4; ++e) {
          s1[m][e] += acc[m][j][e];
          s2[m][e] += acc[m][j][e] * acc[m][j][e];
        }
#pragma unroll
    for (int o = 1; o < 16; o <<= 1)
#pragma unroll
      for (int m = 0; m < 2; ++m)
#pragma unroll
        for (int e = 0; e < 4; ++e) {
          s1[m][e] += __shfl_xor(s1[m][e], o);
          s2[m][e] += __shfl_xor(s2[m][e], o);
        }
    if (lr == 0) {
#pragma unroll
      for (int m = 0; m < 2; ++m)
#pragma unroll
        for (int e = 0; e < 4; ++e) {
          const int row = wm * 32 + m * 16 + lk * 4 + e;
          red[row][wn][0] = s1[m][e];
          red[row][wn][1] = s2[m][e];
        }
    }
    barrier_lds();
#pragma unroll
    for (int m = 0; m < 2; ++m)
#pragma unroll
      for (int e = 0; e < 4; ++e) {
        const int row = wm * 32 + m * 16 + lk * 4 + e;
        const float S1 =
            red[row][0][0] + red[row][1][0] + red[row][2][0] + red[row][3][0];
        const float S2 =
            red[row][0][1] + red[row][1][1] + red[row][2][1] + red[row][3][1];
        const float mu = S1 * (1.0f / 256.0f);
        const float var = S2 * (1.0f / 256.0f) - mu * mu;
        mean[m][e] = mu;
        rstd[m][e] = rsqrtf(var + 1e-5f);
      }
  };

  f32x4 acc2[2][4];
  // ---- init acc2 = x + ba2 (residual + bias folded into accumulator) ----
#pragma unroll
  for (int j = 0; j < 4; ++j) {
    const int col = colb + j * 16 + lr;
    const float bv = ba2[col];
#pragma unroll
    for (int m = 0; m < 2; ++m)
#pragma unroll
      for (int e = 0; e < 4; ++e) {
        const int row = wm * 32 + m * 16 + lk * 4 + e;
        acc2[m][j][e] = bv + feats[(rowbase + row) * 256 + col];
      }
  }
  // ---- stage x (bf16, swizzled) into regA ----
#pragma unroll
  for (int it = 0; it < 4; ++it) {
    const int c = tid + it * 512;  // chunk id, 2048 total
    const int row = c >> 5, cc = c & 31;
    const float* src = feats + (rowbase + row) * 256 + cc * 8;
    bf16x8 v;
#pragma unroll
    for (int e = 0; e < 8; ++e) v[e] = (__bf16)src[e];
    *(bf16x8*)(regA + row * 512 + ((cc ^ (row & 7)) << 4)) = v;
  }
  __syncthreads();  // once per block; full drain ok (nothing prefetched yet)
  prestage(pa1, 0, 64);

  // ================= A-phase: x -> h -> adp out (chunk-fused) ================
#pragma unroll 1
  for (int ch = 0; ch < 4; ++ch) {
    f32x4 acc1[2][4];
#pragma unroll
    for (int j = 0; j < 4; ++j) {
      const float bv = ba1[ch * 256 + colb + j * 16 + lr];
#pragma unroll
      for (int m = 0; m < 2; ++m) acc1[m][j] = {bv, bv, bv, bv};
    }
    mmG(regA, pa1, ch * 16, 64, acc1);  // A1: h_chunk = x @ wa1[:, ch]
    prestage(pa2, ch * 128, 16);        // fill A2 pipeline under store_gelu
    // no barrier needed before store_gelu: regB's last cross-wave readers
    // (mmG A2 of ch-1) are covered by A1's 8 in-loop barriers
    store_gelu(regB, acc1);
    barrier_lds();
    mmG(regB, pa2, ch * 128, 16, acc2);  // A2: acc2 += h_chunk @ wa2[ch, :]
    if (ch < 3) prestage(pa1, (ch + 1) * 16, 64);
  }
  prestage(pf1, 0, 16);  // B1 pipeline fill hides under LN1 + motion staging

  // ---- LN1 in fragment layout -> regA bf16; stage motion -> regM ----
  {
    float mean[2][4], rstd[2][4];
    ln_stats(acc2, mean, rstd);  // internal barrier: A2 done by all waves
#pragma unroll
    for (int j = 0; j < 4; ++j) {
      const int col = colb + j * 16 + lr;
      const float gv = ng[col], bv = nb[col];
#pragma unroll
      for (int m = 0; m < 2; ++m)
#pragma unroll
        for (int e = 0; e < 4; ++e) {
          const int row = wm * 32 + m * 16 + lk * 4 + e;
          const float v = (acc2[m][j][e] - mean[m][e]) * rstd[m][e] * gv + bv;
          *(__bf16*)(regA + row * 512 + (((col >> 3) ^ (row & 7)) << 4) +
                     ((col & 7) << 1)) = (__bf16)v;
        }
    }
    if (tid < 256) {  // motion tile -> regM (regB free after ln_stats barrier)
      const int row = tid >> 2, cc = tid & 3;
      const float* src = motion + (rowbase + row) * 32 + cc * 8;
      bf16x8 v;
#pragma unroll
      for (int e = 0; e < 8; ++e) v[e] = (__bf16)src[e];
      *(bf16x8*)(regM + row * 64 + ((cc ^ (row & 3)) << 4)) = v;
    }
  }
  barrier_lds();

  // ================= B-phase: fus MLP =================
  {
    f32x4 accB[2][4];
#pragma unroll
    for (int j = 0; j < 4; ++j) {
      const float bv = bf1[colb + j * 16 + lr];
#pragma unroll
      for (int m = 0; m < 2; ++m) accB[m][j] = {bv, bv, bv, bv};
    }
    mmG(regA, pf1, 0, 16, accB);  // B1 main: LN1-out @ wf1[:256,:]
    {                             // B1 motion: K=32 from regM (direct-global B)
      bf16x8 a[2];
#pragma unroll
      for (int m = 0; m < 2; ++m) {
        const int row = wm * 32 + m * 16 + lr;
        a[m] = *(const bf16x8*)(regM + row * 64 + ((lk ^ (row & 3)) << 4));
      }
#pragma unroll
      for (int j = 0; j < 4; ++j) {
        const bf16x8 b = ldb(pf1, 128 + wn * 4 + j);
#pragma unroll
        for (int m = 0; m < 2; ++m)
          accB[m][j] =
              __builtin_amdgcn_mfma_f32_16x16x32_bf16(a[m], b, accB[m][j], 0, 0, 0);
      }
    }
    prestage(pf2, 0, 16);  // B2 pipeline fill hides under store_gelu
    barrier_lds();         // needed: other waves' regM reads vs regB writes
    store_gelu(regB, accB);  // g1 (overwrites motion alias: ok)
    barrier_lds();
    // B2: f = g1 @ wf2 + bf2 ; keep f exactly via acc2 = f + bn2
    f32x4 accD[2][4];
#pragma unroll
    for (int j = 0; j < 4; ++j) {
      const float bv = bf2[colb + j * 16 + lr];
#pragma unroll
      for (int m = 0; m < 2; ++m) accD[m][j] = {bv, bv, bv, bv};
    }
    mmG(regB, pf2, 0, 16, accD);
    prestage(pn1, 0, 64);  // C1 pipeline fill hides under B epilogue
#pragma unroll
    for (int j = 0; j < 4; ++j) {
      const int col = colb + j * 16 + lr;
      const float bv = bn2[col];
#pragma unroll
      for (int m = 0; m < 2; ++m)
#pragma unroll
        for (int e = 0; e < 4; ++e) {
          const int row = wm * 32 + m * 16 + lk * 4 + e;
          const float fv = accD[m][j][e];
          *(__bf16*)(regA + row * 512 + (((col >> 3) ^ (row & 7)) << 4) +
                     ((col & 7) << 1)) = (__bf16)fv;  // C1 input
          acc2[m][j][e] = fv + bv;  // residual + bias folded into C accum
        }
    }
  }
  barrier_lds();

  // ================= C-phase: ffn on f (chunk-fused) =================
#pragma unroll 1
  for (int ch = 0; ch < 4; ++ch) {
    f32x4 acc1[2][4];
#pragma unroll
    for (int j = 0; j < 4; ++j) {
      const float bv = bn1[ch * 256 + colb + j * 16 + lr];
#pragma unroll
      for (int m = 0; m < 2; ++m) acc1[m][j] = {bv, bv, bv, bv};
    }
    mmG(regA, pn1, ch * 16, 64, acc1);
    prestage(pn2, ch * 128, 16);
    store_gelu(regB, acc1);
    barrier_lds();
    mmG(regB, pn2, ch * 128, 16, acc2);
    if (ch < 3) prestage(pn1, (ch + 1) * 16, 64);
  }

  // ---- LN2 in fragment layout -> global out ----
  {
    float mean[2][4], rstd[2][4];
    ln_stats(acc2, mean, rstd);
#pragma unroll
    for (int j = 0; j < 4; ++j) {
      const int col = colb + j * 16 + lr;
      const float gv = fg[col], bv = fb[col];
#pragma unroll
      for (int m = 0; m < 2; ++m)
#pragma unroll
        for (int e = 0; e < 4; ++e) {
          const int row = wm * 32 + m * 16 + lk * 4 + e;
          out[(rowbase + row) * 256 + col] =
              (acc2[m][j][e] - mean[m][e]) * rstd[m][e] * gv + bv;
        }
    }
  }
}

}  // namespace

extern "C" void kernel_launch(void* const* d_in, const int* in_sizes, int n_in,
                              void* d_out, int out_size, void* d_ws, size_t ws_size,
                              hipStream_t stream) {
  const float* feats = (const float*)d_in[0];
  const float* boxes = (const float*)d_in[1];
  const void*  masks = d_in[2];
  const int*   times = (const int*)d_in[3];
  const float* wa1 = (const float*)d_in[4];
  const float* ba1 = (const float*)d_in[5];
  const float* wa2 = (const float*)d_in[6];
  const float* ba2 = (const float*)d_in[7];
  const float* ng  = (const float*)d_in[8];
  const float* nb  = (const float*)d_in[9];
  const float* mw1 = (const float*)d_in[10];
  const float* mb1 = (const float*)d_in[11];
  const float* mw2 = (const float*)d_in[12];
  const float* mb2 = (const float*)d_in[13];
  const float* wf1 = (const float*)d_in[14];
  const float* bf1 = (const float*)d_in[15];
  const float* wf2 = (const float*)d_in[16];
  const float* bf2 = (const float*)d_in[17];
  const float* wn1 = (const float*)d_in[18];
  const float* bn1 = (const float*)d_in[19];
  const float* wn2 = (const float*)d_in[20];
  const float* bn2 = (const float*)d_in[21];
  const float* fg  = (const float*)d_in[22];
  const float* fb  = (const float*)d_in[23];

  float* out_fused = (float*)d_out;
  float* out_motion = out_fused + FUSED_N;
  int* flag = (int*)d_ws;
  __bf16* pw = (__bf16*)((char*)d_ws + 256);

  const int mask_elems = in_sizes[2];  // 153600

  k_zero_flag<<<1, 1, 0, stream>>>(flag);
  k_detect_mask<<<(mask_elems + 255) / 256, 256, 0, stream>>>(
      (const unsigned char*)masks, mask_elems, flag);
  k_motion<<<(BG_ * N_) / 4, 256, 0, stream>>>(boxes, masks, times, mw1, mb1, mw2,
                                               mb2, out_motion, flag);

  auto packn = [&](const float* W, long off, int K, int NN) {
    const int total = (K / 32) * (NN / 16) * 64;
    k_pack<<<(total + 255) / 256, 256, 0, stream>>>(W, pw + off, K, NN);
  };
  packn(wa1, PA1, 256, 1024);
  packn(wa2, PA2, 1024, 256);
  packn(wf1, PF1, 288, 256);
  packn(wf2, PF2, 256, 256);
  packn(wn1, PN1, 256, 1024);
  packn(wn2, PN2, 1024, 256);

  k_mfma<<<(int)(MROWS_ / MB), 512, 0, stream>>>(
      feats, out_motion, pw, ba1, ba2, ng, nb, bf1, bf2, bn1, bn2, fg, fb,
      out_fused);
}

// Round 2
// 671.616 us; speedup vs baseline: 1.2302x; 1.2170x over previous
//
#include <hip/hip_runtime.h>

typedef __bf16 bf16x8 __attribute__((ext_vector_type(8)));
typedef float f32x4 __attribute__((ext_vector_type(4)));

namespace {

constexpr int T_ = 64;
constexpr int N_ = 300;
constexpr int MD_ = 32;
constexpr int BG_ = 8;                        // B*G
constexpr long MROWS_ = (long)BG_ * T_ * N_;  // 153600
constexpr long FUSED_N = MROWS_ * 256;        // 39321600
constexpr int MB = 128;                       // rows per block (main kernel)

// packed-weight offsets in bf16 elements inside d_ws (after 256-byte header)
constexpr long PA1 = 0;        // adp_w1 [256][1024]
constexpr long PA2 = 262144;   // adp_w2 [1024][256]
constexpr long PF1 = 524288;   // fus_w1 [288][256]
constexpr long PF2 = 598016;   // fus_w2 [256][256]
constexpr long PN1 = 663552;   // ffn_w1 [256][1024]
constexpr long PN2 = 925696;   // ffn_w2 [1024][256]

// fast tanh-form GELU: |delta| vs erf-GELU <= ~2e-3 (under bf16 noise)
__device__ __forceinline__ float gelu_f(float x) {
  const float x2 = x * x;
  const float z2 = x * fmaf(x2, 0.07135481627f, 1.5957691216f);  // 2*z
  const float t = __builtin_amdgcn_rcpf(1.0f + __expf(z2));      // (1-tanh z)/2
  return x * (1.0f - t);
}

__device__ __forceinline__ float gelu_exact(float x) {
  return 0.5f * x * (1.0f + erff(x * 0.7071067811865476f));
}

// ---------------- mask dtype detection ----------------
__global__ void k_zero_flag(int* f) { *f = 0; }

__global__ void k_detect_mask(const unsigned char* __restrict__ m, int nbytes,
                              int* __restrict__ f) {
  int i = blockIdx.x * 256 + threadIdx.x;
  if (i < nbytes && (i & 3) != 0 && m[i] != 0) atomicOr(f, 1);
}

// ---------------- motion features (unchanged, verified) ----------------
__global__ __launch_bounds__(256)
void k_motion(const float* __restrict__ boxes, const void* __restrict__ masks,
              const int* __restrict__ times,
              const float* __restrict__ mw1, const float* __restrict__ mb1,
              const float* __restrict__ mw2, const float* __restrict__ mb2,
              float* __restrict__ motion, const int* __restrict__ flagp) {
  __shared__ int slot[4][T_];
  __shared__ int sts[4][T_];
  __shared__ float sbx[4][T_][4];
  __shared__ float otile[4][T_][MD_];
  const int tid = threadIdx.x;
  const int w = tid >> 6, l = tid & 63;
  const int traj = blockIdx.x * 4 + w;
  const int bg = traj / N_, n = traj - bg * N_;
  const int isbool = *flagp;
  const long idx = ((long)bg * T_ + l) * N_ + n;  // t = l
  const bool msk = isbool ? (((const unsigned char*)masks)[idx] != 0)
                          : (((const int*)masks)[idx] != 0);
  const bool valid = !msk;
  const int tm = times[idx];

  slot[w][l] = -1;
  sts[w][l] = 0;
  *(float4*)&sbx[w][l][0] = make_float4(0.f, 0.f, 0.f, 0.f);
  __syncthreads();
  if (valid) slot[w][tm] = l;
  __syncthreads();

  const int ot = slot[w][l];
  const bool vp = ot >= 0;
  const unsigned long long bal = __ballot(vp);
  const int cnt = __builtin_popcountll(bal);
  const int pos = __builtin_popcountll(bal & ((1ull << l) - 1ull));
  if (vp) {
    sts[w][pos] = l;
    const float4 bx = *(const float4*)(boxes + (((long)bg * T_ + ot) * N_ + n) * 4);
    *(float4*)&sbx[w][pos][0] = bx;
  }
  __syncthreads();

  const int stp = sts[w][l];
  const int stm1 = sts[w][(l + 63) & 63];
  const float4 sb = *(const float4*)&sbx[w][l][0];
  const float4 sbm = *(const float4*)&sbx[w][(l + 63) & 63][0];
  const float dt = (float)max(stp - stm1, 1);
  const float inv = 1.0f / dt;
  const bool okv = (l >= 1) && (l < cnt);
  float v0 = okv ? (sb.x - sbm.x) * inv : 0.f;
  float v1 = okv ? (sb.y - sbm.y) * inv : 0.f;
  float v2 = okv ? (sb.z - sbm.z) * inv : 0.f;
  float v3 = okv ? (sb.w - sbm.w) * inv : 0.f;
  const float p0 = __shfl_up(v0, 1, 64);
  const float p1 = __shfl_up(v1, 1, 64);
  const float p2 = __shfl_up(v2, 1, 64);
  const float p3 = __shfl_up(v3, 1, 64);
  const bool oka = (l >= 2) && (l < cnt);
  const float a0 = oka ? (v0 - p0) * inv : 0.f;
  const float a1 = oka ? (v1 - p1) * inv : 0.f;
  const float a2 = oka ? (v2 - p2) * inv : 0.f;
  const float a3 = oka ? (v3 - p3) * inv : 0.f;

  const float mv[12] = {sb.x, sb.y, sb.z, sb.w, v0, v1, v2, v3, a0, a1, a2, a3};
  float e1[16];
#pragma unroll
  for (int i = 0; i < 16; ++i) {
    float a = mb1[i];
#pragma unroll
    for (int c = 0; c < 12; ++c) a = fmaf(mv[c], mw1[c * 16 + i], a);
    e1[i] = gelu_exact(a);
  }
  float enc[32];
#pragma unroll
  for (int o = 0; o < 32; ++o) {
    float a = mb2[o];
#pragma unroll
    for (int i = 0; i < 16; ++i) a = fmaf(e1[i], mw2[i * 32 + o], a);
    enc[o] = a;
  }

#pragma unroll
  for (int c = 0; c < 32; c += 4)
    *(float4*)&otile[w][l][c] = make_float4(0.f, 0.f, 0.f, 0.f);
  __syncthreads();
  if (l < cnt && cnt >= 2) {
#pragma unroll
    for (int c = 0; c < 32; ++c) otile[w][stp][c] = enc[c];
  }
  __syncthreads();

  float* mbase = motion + ((long)bg * T_ * N_ + n) * MD_;
  const float4* srcv = (const float4*)&otile[w][l][0];
  float4* dstv = (float4*)(mbase + (long)l * N_ * MD_);
#pragma unroll
  for (int q = 0; q < 8; ++q) dstv[q] = srcv[q];
}

// ---------------- weight packing: f32 row-major -> bf16 MFMA-B fragments ----
// frag f = kb*(NN/16)+nt holds B[kb*32 + (l>>4)*8 + e][nt*16 + (l&15)],
// stored lane-contiguous: P[(f*64 + l)*8 + e]
__global__ void k_pack(const float* __restrict__ W, __bf16* __restrict__ P,
                       int K, int NN) {
  int gid = blockIdx.x * 256 + threadIdx.x;
  int total = (K >> 5) * (NN >> 4) * 64;
  if (gid >= total) return;
  int l = gid & 63, f = gid >> 6;
  int NT = NN >> 4;
  int kb = f / NT, nt = f - kb * NT;
  int krow = kb * 32 + (l >> 4) * 8;
  int col = nt * 16 + (l & 15);
  bf16x8 v;
#pragma unroll
  for (int e = 0; e < 8; ++e) v[e] = (__bf16)W[(long)(krow + e) * NN + col];
  *(bf16x8*)(P + (long)gid * 8) = v;
}

// ---------------- fused MFMA row pipeline ----------------
// R11 structure: free-running waves, B-operands DIRECT FROM GLOBAL (L2).
// Post-mortem of R9/R10: the per-K-step {barrier; burst-ds_read; MFMA}
// lockstep was the bottleneck (counted-vmcnt changed nothing; step time
// ~1500cy vs ~500cy of floors). Weights (2MB packed) are L2-resident and
// shared by all blocks, so B goes global->VGPR (pattern already verified
// by the B1-motion piece), double-buffered 2 K-steps ahead; the compiler
// inserts vmcnt; waves drift freely and hide each other's latency. LDS
// keeps only A-tiles. Wave tile grows 32x64 -> 64x64 (MB 64->128):
// operand-LDS bytes/MFMA drop 768B -> 256B. Barriers: ~23/block (tile
// transitions only). Per-output-element FP accumulation order is
// unchanged -> results bitwise-identical to R9/R10.
__global__ __launch_bounds__(512, 1)
void k_mfma(const float* __restrict__ feats, const float* __restrict__ motion,
            const __bf16* __restrict__ pw,
            const float* __restrict__ ba1, const float* __restrict__ ba2,
            const float* __restrict__ ng, const float* __restrict__ nb,
            const float* __restrict__ bf1, const float* __restrict__ bf2,
            const float* __restrict__ bn1, const float* __restrict__ bn2,
            const float* __restrict__ fg, const float* __restrict__ fb,
            float* __restrict__ out) {
  __shared__ __align__(16) char smem[131072];
  __shared__ float red[MB][4][2];  // per-row cross-wn LN partials
  char* regA = smem;               // [128][256] bf16 swizzled: x / LN1 / f
  char* regB = smem + 65536;       // [128][256] bf16 swizzled: h-chunk / g1
  char* regM = regB;               // motion tile aliases regB[0..8192)

  const int tid = threadIdx.x;
  const int l = tid & 63, wid = tid >> 6;
  const int lr = l & 15, lk = l >> 4;
  const int wr = wid >> 2;    // 0..1 : 64-row half
  const int wn = wid & 3;     // 0..3 : 64-col slice within 256-chunk
  const int colb = wn * 64;
  const long rowbase = (long)blockIdx.x * MB;

  const __bf16* pa1 = pw + PA1;
  const __bf16* pa2 = pw + PA2;
  const __bf16* pf1 = pw + PF1;
  const __bf16* pf2 = pw + PF2;
  const __bf16* pn1 = pw + PN1;
  const __bf16* pn2 = pw + PN2;

  auto lda = [&](const char* reg, int kb, int m) -> bf16x8 {
    const int row = wr * 64 + m * 16 + lr;
    return *(const bf16x8*)(reg + row * 512 +
                            ((((kb << 2) + lk) ^ (row & 7)) << 4));
  };
  auto ldb = [&](const __bf16* pb, int frag) -> bf16x8 {  // direct global
    return *(const bf16x8*)(pb + ((long)frag << 9) + (l << 3));
  };
  // K=256 chunk GEMM, 8 kb-steps; A from LDS, B from global (L2) with
  // 2-step register double-buffer; no barriers, no manual waitcnts.
  auto mmL2 = [&](const char* reg, const __bf16* pb, long fragbase, int NT,
                  f32x4 (&acc)[4][4]) {
    const __bf16* bbase = pb + ((fragbase + wn * 4) << 9) + ((long)l << 3);
    const long kstride = (long)NT << 9;  // bf16 elems per kb-slab
    bf16x8 bA[4], bB[4];
#pragma unroll
    for (int j = 0; j < 4; ++j)
      bA[j] = *(const bf16x8*)(bbase + ((long)j << 9));
#pragma unroll
    for (int j = 0; j < 4; ++j)
      bB[j] = *(const bf16x8*)(bbase + kstride + ((long)j << 9));
#pragma unroll
    for (int kb = 0; kb < 8; ++kb) {
      bf16x8 a[4];
#pragma unroll
      for (int m = 0; m < 4; ++m) a[m] = lda(reg, kb, m);
      __builtin_amdgcn_s_setprio(1);
#pragma unroll
      for (int j = 0; j < 4; ++j) {
        const bf16x8 b = (kb & 1) ? bB[j] : bA[j];
#pragma unroll
        for (int m = 0; m < 4; ++m)
          acc[m][j] =
              __builtin_amdgcn_mfma_f32_16x16x32_bf16(a[m], b, acc[m][j], 0, 0, 0);
      }
      __builtin_amdgcn_s_setprio(0);
      if (kb < 6) {
#pragma unroll
        for (int j = 0; j < 4; ++j) {
          const bf16x8 v =
              *(const bf16x8*)(bbase + (long)(kb + 2) * kstride + ((long)j << 9));
          if (kb & 1) bB[j] = v; else bA[j] = v;
        }
      }
    }
  };
  // store gelu(acc) as bf16 into swizzled [128][256] tile
  auto store_gelu = [&](char* reg, const f32x4 (&acc)[4][4]) {
#pragma unroll
    for (int j = 0; j < 4; ++j) {
      const int col = colb + j * 16 + lr;
#pragma unroll
      for (int m = 0; m < 4; ++m)
#pragma unroll
        for (int e = 0; e < 4; ++e) {
          const int row = wr * 64 + m * 16 + lk * 4 + e;
          *(__bf16*)(reg + row * 512 + (((col >> 3) ^ (row & 7)) << 4) +
                     ((col & 7) << 1)) = (__bf16)gelu_f(acc[m][j][e]);
        }
    }
  };
  // fragment-layout LN stats: mean/rstd per owned row (m,e)
  auto ln_stats = [&](const f32x4 (&acc)[4][4], float (&mean)[4][4],
                      float (&rstd)[4][4]) {
    float s1[4][4], s2[4][4];
#pragma unroll
    for (int m = 0; m < 4; ++m)
#pragma unroll
      for (int e = 0; e < 4; ++e) { s1[m][e] = 0.f; s2[m][e] = 0.f; }
#pragma unroll
    for (int m = 0; m < 4; ++m)
#pragma unroll
      for (int j = 0; j < 4; ++j)
#pragma unroll
        for (int e = 0; e < 4; ++e) {
          s1[m][e] += acc[m][j][e];
          s2[m][e] += acc[m][j][e] * acc[m][j][e];
        }
#pragma unroll
    for (int o = 1; o < 16; o <<= 1)
#pragma unroll
      for (int m = 0; m < 4; ++m)
#pragma unroll
        for (int e = 0; e < 4; ++e) {
          s1[m][e] += __shfl_xor(s1[m][e], o);
          s2[m][e] += __shfl_xor(s2[m][e], o);
        }
    if (lr == 0) {
#pragma unroll
      for (int m = 0; m < 4; ++m)
#pragma unroll
        for (int e = 0; e < 4; ++e) {
          const int row = wr * 64 + m * 16 + lk * 4 + e;
          red[row][wn][0] = s1[m][e];
          red[row][wn][1] = s2[m][e];
        }
    }
    __syncthreads();
#pragma unroll
    for (int m = 0; m < 4; ++m)
#pragma unroll
      for (int e = 0; e < 4; ++e) {
        const int row = wr * 64 + m * 16 + lk * 4 + e;
        const float S1 =
            red[row][0][0] + red[row][1][0] + red[row][2][0] + red[row][3][0];
        const float S2 =
            red[row][0][1] + red[row][1][1] + red[row][2][1] + red[row][3][1];
        const float mu = S1 * (1.0f / 256.0f);
        const float var = S2 * (1.0f / 256.0f) - mu * mu;
        mean[m][e] = mu;
        rstd[m][e] = rsqrtf(var + 1e-5f);
      }
  };

  f32x4 acc2[4][4];
  // ---- init acc2 = x + ba2 (residual + bias folded into accumulator) ----
#pragma unroll
  for (int j = 0; j < 4; ++j) {
    const int col = colb + j * 16 + lr;
    const float bv = ba2[col];
#pragma unroll
    for (int m = 0; m < 4; ++m)
#pragma unroll
      for (int e = 0; e < 4; ++e) {
        const int row = wr * 64 + m * 16 + lk * 4 + e;
        acc2[m][j][e] = bv + feats[(rowbase + row) * 256 + col];
      }
  }
  // ---- stage x (bf16, swizzled) into regA ----
#pragma unroll
  for (int it = 0; it < 8; ++it) {
    const int c = tid + it * 512;  // chunk id, 4096 total
    const int row = c >> 5, cc = c & 31;
    const float* src = feats + (rowbase + row) * 256 + cc * 8;
    bf16x8 v;
#pragma unroll
    for (int e = 0; e < 8; ++e) v[e] = (__bf16)src[e];
    *(bf16x8*)(regA + row * 512 + ((cc ^ (row & 7)) << 4)) = v;
  }
  __syncthreads();

  // ================= A-phase: x -> h -> adp out (chunk-fused) ================
#pragma unroll 1
  for (int ch = 0; ch < 4; ++ch) {
    f32x4 acc1[4][4];
#pragma unroll
    for (int j = 0; j < 4; ++j) {
      const float bv = ba1[ch * 256 + colb + j * 16 + lr];
#pragma unroll
      for (int m = 0; m < 4; ++m) acc1[m][j] = {bv, bv, bv, bv};
    }
    mmL2(regA, pa1, ch * 16, 64, acc1);  // A1: h_chunk = x @ wa1[:, ch]
    __syncthreads();                     // prev A2 regB readers done
    store_gelu(regB, acc1);
    __syncthreads();
    mmL2(regB, pa2, ch * 128, 16, acc2);  // A2: acc2 += h_chunk @ wa2[ch, :]
  }

  // ---- LN1 in fragment layout -> regA bf16; stage motion -> regM ----
  {
    float mean[4][4], rstd[4][4];
    ln_stats(acc2, mean, rstd);  // internal sync: A2 done by all waves
#pragma unroll
    for (int j = 0; j < 4; ++j) {
      const int col = colb + j * 16 + lr;
      const float gv = ng[col], bv = nb[col];
#pragma unroll
      for (int m = 0; m < 4; ++m)
#pragma unroll
        for (int e = 0; e < 4; ++e) {
          const int row = wr * 64 + m * 16 + lk * 4 + e;
          const float v = (acc2[m][j][e] - mean[m][e]) * rstd[m][e] * gv + bv;
          *(__bf16*)(regA + row * 512 + (((col >> 3) ^ (row & 7)) << 4) +
                     ((col & 7) << 1)) = (__bf16)v;
        }
    }
    {  // motion tile -> regM (regB free after ln_stats sync); 128x32 bf16
      const int row = tid >> 2, cc = tid & 3;
      const float* src = motion + (rowbase + row) * 32 + cc * 8;
      bf16x8 v;
#pragma unroll
      for (int e = 0; e < 8; ++e) v[e] = (__bf16)src[e];
      *(bf16x8*)(regM + row * 64 + ((cc ^ (row & 3)) << 4)) = v;
    }
  }
  __syncthreads();

  // ================= B-phase: fus MLP =================
  {
    f32x4 accB[4][4];
#pragma unroll
    for (int j = 0; j < 4; ++j) {
      const float bv = bf1[colb + j * 16 + lr];
#pragma unroll
      for (int m = 0; m < 4; ++m) accB[m][j] = {bv, bv, bv, bv};
    }
    mmL2(regA, pf1, 0, 16, accB);  // B1 main: LN1-out @ wf1[:256,:]
    {                              // B1 motion: K=32 from regM (direct-global B)
      bf16x8 a[4];
#pragma unroll
      for (int m = 0; m < 4; ++m) {
        const int row = wr * 64 + m * 16 + lr;
        a[m] = *(const bf16x8*)(regM + row * 64 + ((lk ^ (row & 3)) << 4));
      }
#pragma unroll
      for (int j = 0; j < 4; ++j) {
        const bf16x8 b = ldb(pf1, 128 + wn * 4 + j);
#pragma unroll
        for (int m = 0; m < 4; ++m)
          accB[m][j] =
              __builtin_amdgcn_mfma_f32_16x16x32_bf16(a[m], b, accB[m][j], 0, 0, 0);
      }
    }
    __syncthreads();         // all waves done reading regM/regA for B1
    store_gelu(regB, accB);  // g1 (overwrites motion alias: ok)
    __syncthreads();
    // B2: f = g1 @ wf2 + bf2 ; keep f exactly via acc2 = f + bn2
    f32x4 accD[4][4];
#pragma unroll
    for (int j = 0; j < 4; ++j) {
      const float bv = bf2[colb + j * 16 + lr];
#pragma unroll
      for (int m = 0; m < 4; ++m) accD[m][j] = {bv, bv, bv, bv};
    }
    mmL2(regB, pf2, 0, 16, accD);
#pragma unroll
    for (int j = 0; j < 4; ++j) {
      const int col = colb + j * 16 + lr;
      const float bv = bn2[col];
#pragma unroll
      for (int m = 0; m < 4; ++m)
#pragma unroll
        for (int e = 0; e < 4; ++e) {
          const int row = wr * 64 + m * 16 + lk * 4 + e;
          const float fv = accD[m][j][e];
          *(__bf16*)(regA + row * 512 + (((col >> 3) ^ (row & 7)) << 4) +
                     ((col & 7) << 1)) = (__bf16)fv;  // C1 input
          acc2[m][j][e] = fv + bv;  // residual + bias folded into C accum
        }
    }
  }
  __syncthreads();

  // ================= C-phase: ffn on f (chunk-fused) =================
#pragma unroll 1
  for (int ch = 0; ch < 4; ++ch) {
    f32x4 acc1[4][4];
#pragma unroll
    for (int j = 0; j < 4; ++j) {
      const float bv = bn1[ch * 256 + colb + j * 16 + lr];
#pragma unroll
      for (int m = 0; m < 4; ++m) acc1[m][j] = {bv, bv, bv, bv};
    }
    mmL2(regA, pn1, ch * 16, 64, acc1);
    __syncthreads();  // prev C2 regB readers done
    store_gelu(regB, acc1);
    __syncthreads();
    mmL2(regB, pn2, ch * 128, 16, acc2);
  }

  // ---- LN2 in fragment layout -> global out ----
  {
    float mean[4][4], rstd[4][4];
    ln_stats(acc2, mean, rstd);
#pragma unroll
    for (int j = 0; j < 4; ++j) {
      const int col = colb + j * 16 + lr;
      const float gv = fg[col], bv = fb[col];
#pragma unroll
      for (int m = 0; m < 4; ++m)
#pragma unroll
        for (int e = 0; e < 4; ++e) {
          const int row = wr * 64 + m * 16 + lk * 4 + e;
          out[(rowbase + row) * 256 + col] =
              (acc2[m][j][e] - mean[m][e]) * rstd[m][e] * gv + bv;
        }
    }
  }
}

}  // namespace

extern "C" void kernel_launch(void* const* d_in, const int* in_sizes, int n_in,
                              void* d_out, int out_size, void* d_ws, size_t ws_size,
                              hipStream_t stream) {
  const float* feats = (const float*)d_in[0];
  const float* boxes = (const float*)d_in[1];
  const void*  masks = d_in[2];
  const int*   times = (const int*)d_in[3];
  const float* wa1 = (const float*)d_in[4];
  const float* ba1 = (const float*)d_in[5];
  const float* wa2 = (const float*)d_in[6];
  const float* ba2 = (const float*)d_in[7];
  const float* ng  = (const float*)d_in[8];
  const float* nb  = (const float*)d_in[9];
  const float* mw1 = (const float*)d_in[10];
  const float* mb1 = (const float*)d_in[11];
  const float* mw2 = (const float*)d_in[12];
  const float* mb2 = (const float*)d_in[13];
  const float* wf1 = (const float*)d_in[14];
  const float* bf1 = (const float*)d_in[15];
  const float* wf2 = (const float*)d_in[16];
  const float* bf2 = (const float*)d_in[17];
  const float* wn1 = (const float*)d_in[18];
  const float* bn1 = (const float*)d_in[19];
  const float* wn2 = (const float*)d_in[20];
  const float* bn2 = (const float*)d_in[21];
  const float* fg  = (const float*)d_in[22];
  const float* fb  = (const float*)d_in[23];

  float* out_fused = (float*)d_out;
  float* out_motion = out_fused + FUSED_N;
  int* flag = (int*)d_ws;
  __bf16* pw = (__bf16*)((char*)d_ws + 256);

  const int mask_elems = in_sizes[2];  // 153600

  k_zero_flag<<<1, 1, 0, stream>>>(flag);
  k_detect_mask<<<(mask_elems + 255) / 256, 256, 0, stream>>>(
      (const unsigned char*)masks, mask_elems, flag);
  k_motion<<<(BG_ * N_) / 4, 256, 0, stream>>>(boxes, masks, times, mw1, mb1, mw2,
                                               mb2, out_motion, flag);

  auto packn = [&](const float* W, long off, int K, int NN) {
    const int total = (K / 32) * (NN / 16) * 64;
    k_pack<<<(total + 255) / 256, 256, 0, stream>>>(W, pw + off, K, NN);
  };
  packn(wa1, PA1, 256, 1024);
  packn(wa2, PA2, 1024, 256);
  packn(wf1, PF1, 288, 256);
  packn(wf2, PF2, 256, 256);
  packn(wn1, PN1, 256, 1024);
  packn(wn2, PN2, 1024, 256);

  k_mfma<<<(int)(MROWS_ / MB), 512, 0, stream>>>(
      feats, out_motion, pw, ba1, ba2, ng, nb, bf1, bf2, bn1, bn2, fg, fb,
      out_fused);
}

// Round 3
// 636.064 us; speedup vs baseline: 1.2989x; 1.0559x over previous
//
#include <hip/hip_runtime.h>

typedef __bf16 bf16x8 __attribute__((ext_vector_type(8)));
typedef float f32x4 __attribute__((ext_vector_type(4)));

namespace {

constexpr int T_ = 64;
constexpr int N_ = 300;
constexpr int MD_ = 32;
constexpr int BG_ = 8;                        // B*G
constexpr long MROWS_ = (long)BG_ * T_ * N_;  // 153600
constexpr long FUSED_N = MROWS_ * 256;        // 39321600
constexpr int MB = 128;                       // rows per block (main kernel)

// packed-weight offsets in bf16 elements inside d_ws (after 256-byte header)
constexpr long PA1 = 0;        // adp_w1 [256][1024]
constexpr long PA2 = 262144;   // adp_w2 [1024][256]
constexpr long PF1 = 524288;   // fus_w1 [288][256]
constexpr long PF2 = 598016;   // fus_w2 [256][256]
constexpr long PN1 = 663552;   // ffn_w1 [256][1024]
constexpr long PN2 = 925696;   // ffn_w2 [1024][256]

// fast tanh-form GELU: |delta| vs erf-GELU <= ~2e-3 (under bf16 noise)
__device__ __forceinline__ float gelu_f(float x) {
  const float x2 = x * x;
  const float z2 = x * fmaf(x2, 0.07135481627f, 1.5957691216f);  // 2*z
  const float t = __builtin_amdgcn_rcpf(1.0f + __expf(z2));      // (1-tanh z)/2
  return x * (1.0f - t);
}

__device__ __forceinline__ float gelu_exact(float x) {
  return 0.5f * x * (1.0f + erff(x * 0.7071067811865476f));
}

// ---------------- mask dtype detection ----------------
__global__ void k_zero_flag(int* f) { *f = 0; }

__global__ void k_detect_mask(const unsigned char* __restrict__ m, int nbytes,
                              int* __restrict__ f) {
  int i = blockIdx.x * 256 + threadIdx.x;
  if (i < nbytes && (i & 3) != 0 && m[i] != 0) atomicOr(f, 1);
}

// ---------------- motion features (unchanged, verified) ----------------
__global__ __launch_bounds__(256)
void k_motion(const float* __restrict__ boxes, const void* __restrict__ masks,
              const int* __restrict__ times,
              const float* __restrict__ mw1, const float* __restrict__ mb1,
              const float* __restrict__ mw2, const float* __restrict__ mb2,
              float* __restrict__ motion, const int* __restrict__ flagp) {
  __shared__ int slot[4][T_];
  __shared__ int sts[4][T_];
  __shared__ float sbx[4][T_][4];
  __shared__ float otile[4][T_][MD_];
  const int tid = threadIdx.x;
  const int w = tid >> 6, l = tid & 63;
  const int traj = blockIdx.x * 4 + w;
  const int bg = traj / N_, n = traj - bg * N_;
  const int isbool = *flagp;
  const long idx = ((long)bg * T_ + l) * N_ + n;  // t = l
  const bool msk = isbool ? (((const unsigned char*)masks)[idx] != 0)
                          : (((const int*)masks)[idx] != 0);
  const bool valid = !msk;
  const int tm = times[idx];

  slot[w][l] = -1;
  sts[w][l] = 0;
  *(float4*)&sbx[w][l][0] = make_float4(0.f, 0.f, 0.f, 0.f);
  __syncthreads();
  if (valid) slot[w][tm] = l;
  __syncthreads();

  const int ot = slot[w][l];
  const bool vp = ot >= 0;
  const unsigned long long bal = __ballot(vp);
  const int cnt = __builtin_popcountll(bal);
  const int pos = __builtin_popcountll(bal & ((1ull << l) - 1ull));
  if (vp) {
    sts[w][pos] = l;
    const float4 bx = *(const float4*)(boxes + (((long)bg * T_ + ot) * N_ + n) * 4);
    *(float4*)&sbx[w][pos][0] = bx;
  }
  __syncthreads();

  const int stp = sts[w][l];
  const int stm1 = sts[w][(l + 63) & 63];
  const float4 sb = *(const float4*)&sbx[w][l][0];
  const float4 sbm = *(const float4*)&sbx[w][(l + 63) & 63][0];
  const float dt = (float)max(stp - stm1, 1);
  const float inv = 1.0f / dt;
  const bool okv = (l >= 1) && (l < cnt);
  float v0 = okv ? (sb.x - sbm.x) * inv : 0.f;
  float v1 = okv ? (sb.y - sbm.y) * inv : 0.f;
  float v2 = okv ? (sb.z - sbm.z) * inv : 0.f;
  float v3 = okv ? (sb.w - sbm.w) * inv : 0.f;
  const float p0 = __shfl_up(v0, 1, 64);
  const float p1 = __shfl_up(v1, 1, 64);
  const float p2 = __shfl_up(v2, 1, 64);
  const float p3 = __shfl_up(v3, 1, 64);
  const bool oka = (l >= 2) && (l < cnt);
  const float a0 = oka ? (v0 - p0) * inv : 0.f;
  const float a1 = oka ? (v1 - p1) * inv : 0.f;
  const float a2 = oka ? (v2 - p2) * inv : 0.f;
  const float a3 = oka ? (v3 - p3) * inv : 0.f;

  const float mv[12] = {sb.x, sb.y, sb.z, sb.w, v0, v1, v2, v3, a0, a1, a2, a3};
  float e1[16];
#pragma unroll
  for (int i = 0; i < 16; ++i) {
    float a = mb1[i];
#pragma unroll
    for (int c = 0; c < 12; ++c) a = fmaf(mv[c], mw1[c * 16 + i], a);
    e1[i] = gelu_exact(a);
  }
  float enc[32];
#pragma unroll
  for (int o = 0; o < 32; ++o) {
    float a = mb2[o];
#pragma unroll
    for (int i = 0; i < 16; ++i) a = fmaf(e1[i], mw2[i * 32 + o], a);
    enc[o] = a;
  }

#pragma unroll
  for (int c = 0; c < 32; c += 4)
    *(float4*)&otile[w][l][c] = make_float4(0.f, 0.f, 0.f, 0.f);
  __syncthreads();
  if (l < cnt && cnt >= 2) {
#pragma unroll
    for (int c = 0; c < 32; ++c) otile[w][stp][c] = enc[c];
  }
  __syncthreads();

  float* mbase = motion + ((long)bg * T_ * N_ + n) * MD_;
  const float4* srcv = (const float4*)&otile[w][l][0];
  float4* dstv = (float4*)(mbase + (long)l * N_ * MD_);
#pragma unroll
  for (int q = 0; q < 8; ++q) dstv[q] = srcv[q];
}

// ---------------- weight packing: f32 row-major -> bf16 MFMA-B fragments ----
// frag f = kb*(NN/16)+nt holds B[kb*32 + (l>>4)*8 + e][nt*16 + (l&15)],
// stored lane-contiguous: P[(f*64 + l)*8 + e]
__global__ void k_pack(const float* __restrict__ W, __bf16* __restrict__ P,
                       int K, int NN) {
  int gid = blockIdx.x * 256 + threadIdx.x;
  int total = (K >> 5) * (NN >> 4) * 64;
  if (gid >= total) return;
  int l = gid & 63, f = gid >> 6;
  int NT = NN >> 4;
  int kb = f / NT, nt = f - kb * NT;
  int krow = kb * 32 + (l >> 4) * 8;
  int col = nt * 16 + (l & 15);
  bf16x8 v;
#pragma unroll
  for (int e = 0; e < 8; ++e) v[e] = (__bf16)W[(long)(krow + e) * NN + col];
  *(bf16x8*)(P + (long)gid * 8) = v;
}

// GEMM inner: A from LDS tile (row stride 1<<RSH bytes, 16B-group XOR-swizzle
// by (row&7)), B direct from global (L2-resident packed frags), register
// double-buffered 2 kb-steps ahead. KBN = K/32 steps, JN = 16-col frags per
// wave. No barriers, no manual waitcnts: waves free-run.
template <int KBN, int JN, int RSH>
__device__ __forceinline__ void mm_l2(const char* reg, const __bf16* bb,
                                      const long kstride, const int row0,
                                      const int lr, const int lk,
                                      f32x4 (&acc)[4][JN]) {
  bf16x8 bA[JN], bB[JN];
#pragma unroll
  for (int j = 0; j < JN; ++j) bA[j] = *(const bf16x8*)(bb + ((long)j << 9));
  if (KBN > 1) {
#pragma unroll
    for (int j = 0; j < JN; ++j)
      bB[j] = *(const bf16x8*)(bb + kstride + ((long)j << 9));
  }
#pragma unroll
  for (int kb = 0; kb < KBN; ++kb) {
    bf16x8 a[4];
#pragma unroll
    for (int m = 0; m < 4; ++m) {
      const int row = row0 + m * 16 + lr;
      a[m] = *(const bf16x8*)(reg + ((long)row << RSH) +
                              ((((kb << 2) + lk) ^ (row & 7)) << 4));
    }
    __builtin_amdgcn_s_setprio(1);
#pragma unroll
    for (int j = 0; j < JN; ++j) {
      const bf16x8 b = (kb & 1) ? bB[j] : bA[j];
#pragma unroll
      for (int m = 0; m < 4; ++m)
        acc[m][j] =
            __builtin_amdgcn_mfma_f32_16x16x32_bf16(a[m], b, acc[m][j], 0, 0, 0);
    }
    __builtin_amdgcn_s_setprio(0);
    if (kb < KBN - 2) {
#pragma unroll
      for (int j = 0; j < JN; ++j) {
        const bf16x8 v =
            *(const bf16x8*)(bb + (long)(kb + 2) * kstride + ((long)j << 9));
        if (kb & 1) bB[j] = v; else bA[j] = v;
      }
    }
  }
}

// ---------------- fused MFMA row pipeline ----------------
// R12: R11's free-running direct-global-B structure, with peak register
// liveness cut ~40 regs to kill the scratch spill R11's counters exposed
// (WRITE_SIZE 451MB vs 176 ideal = spill write-back). Intermediate N-chunk
// width 256 -> 128: acc1/accB become [4][2] (32 regs), regB shrinks to
// [128][128] (32KB), regM gets its own 8KB (no alias: B-phase sub-split
// reads regM across both halves). Global K accumulation order unchanged ->
// numerics identical. LDS ~109KB, still 1 block/CU.
__global__ __launch_bounds__(512, 1)
void k_mfma(const float* __restrict__ feats, const float* __restrict__ motion,
            const __bf16* __restrict__ pw,
            const float* __restrict__ ba1, const float* __restrict__ ba2,
            const float* __restrict__ ng, const float* __restrict__ nb,
            const float* __restrict__ bf1, const float* __restrict__ bf2,
            const float* __restrict__ bn1, const float* __restrict__ bn2,
            const float* __restrict__ fg, const float* __restrict__ fb,
            float* __restrict__ out) {
  __shared__ __align__(16) char smem[106496];
  __shared__ float red[MB][4][2];  // per-row cross-wn LN partials
  char* regA = smem;               // [128][256] bf16 swizzled: x / LN1 / f
  char* regB = smem + 65536;       // [128][128] bf16 swizzled: h-sub / g1-sub
  char* regM = smem + 98304;       // [128][32] bf16 swizzled motion tile

  const int tid = threadIdx.x;
  const int l = tid & 63, wid = tid >> 6;
  const int lr = l & 15, lk = l >> 4;
  const int wr = wid >> 2;    // 0..1 : 64-row half
  const int wn = wid & 3;     // 0..3 : col slice
  const int colb = wn * 64;   // for 256-wide accumulators
  const int row0 = wr * 64;
  const long rowbase = (long)blockIdx.x * MB;

  const __bf16* pa1 = pw + PA1;
  const __bf16* pa2 = pw + PA2;
  const __bf16* pf1 = pw + PF1;
  const __bf16* pf2 = pw + PF2;
  const __bf16* pn1 = pw + PN1;
  const __bf16* pn2 = pw + PN2;

  auto ldb = [&](const __bf16* pb, int frag) -> bf16x8 {  // direct global
    return *(const bf16x8*)(pb + ((long)frag << 9) + (l << 3));
  };
  // store gelu(acc) as bf16 into swizzled [128][128] tile (256B rows)
  auto store_gelu128 = [&](char* reg, const f32x4 (&acc)[4][2]) {
#pragma unroll
    for (int j = 0; j < 2; ++j) {
      const int col = wn * 32 + j * 16 + lr;
#pragma unroll
      for (int m = 0; m < 4; ++m)
#pragma unroll
        for (int e = 0; e < 4; ++e) {
          const int row = row0 + m * 16 + lk * 4 + e;
          *(__bf16*)(reg + row * 256 + (((col >> 3) ^ (row & 7)) << 4) +
                     ((col & 7) << 1)) = (__bf16)gelu_f(acc[m][j][e]);
        }
    }
  };
  // fragment-layout LN stats: mean/rstd per owned row (m,e)
  auto ln_stats = [&](const f32x4 (&acc)[4][4], float (&mean)[4][4],
                      float (&rstd)[4][4]) {
    float s1[4][4], s2[4][4];
#pragma unroll
    for (int m = 0; m < 4; ++m)
#pragma unroll
      for (int e = 0; e < 4; ++e) { s1[m][e] = 0.f; s2[m][e] = 0.f; }
#pragma unroll
    for (int m = 0; m < 4; ++m)
#pragma unroll
      for (int j = 0; j < 4; ++j)
#pragma unroll
        for (int e = 0; e < 4; ++e) {
          s1[m][e] += acc[m][j][e];
          s2[m][e] += acc[m][j][e] * acc[m][j][e];
        }
#pragma unroll
    for (int o = 1; o < 16; o <<= 1)
#pragma unroll
      for (int m = 0; m < 4; ++m)
#pragma unroll
        for (int e = 0; e < 4; ++e) {
          s1[m][e] += __shfl_xor(s1[m][e], o);
          s2[m][e] += __shfl_xor(s2[m][e], o);
        }
    if (lr == 0) {
#pragma unroll
      for (int m = 0; m < 4; ++m)
#pragma unroll
        for (int e = 0; e < 4; ++e) {
          const int row = row0 + m * 16 + lk * 4 + e;
          red[row][wn][0] = s1[m][e];
          red[row][wn][1] = s2[m][e];
        }
    }
    __syncthreads();
#pragma unroll
    for (int m = 0; m < 4; ++m)
#pragma unroll
      for (int e = 0; e < 4; ++e) {
        const int row = row0 + m * 16 + lk * 4 + e;
        const float S1 =
            red[row][0][0] + red[row][1][0] + red[row][2][0] + red[row][3][0];
        const float S2 =
            red[row][0][1] + red[row][1][1] + red[row][2][1] + red[row][3][1];
        const float mu = S1 * (1.0f / 256.0f);
        const float var = S2 * (1.0f / 256.0f) - mu * mu;
        mean[m][e] = mu;
        rstd[m][e] = rsqrtf(var + 1e-5f);
      }
  };

  f32x4 acc2[4][4];
  // ---- init acc2 = x + ba2 (residual + bias folded into accumulator) ----
#pragma unroll
  for (int j = 0; j < 4; ++j) {
    const int col = colb + j * 16 + lr;
    const float bv = ba2[col];
#pragma unroll
    for (int m = 0; m < 4; ++m)
#pragma unroll
      for (int e = 0; e < 4; ++e) {
        const int row = row0 + m * 16 + lk * 4 + e;
        acc2[m][j][e] = bv + feats[(rowbase + row) * 256 + col];
      }
  }
  // ---- stage x (bf16, swizzled) into regA ----
#pragma unroll
  for (int it = 0; it < 8; ++it) {
    const int c = tid + it * 512;  // chunk id, 4096 total
    const int row = c >> 5, cc = c & 31;
    const float* src = feats + (rowbase + row) * 256 + cc * 8;
    bf16x8 v;
#pragma unroll
    for (int e = 0; e < 8; ++e) v[e] = (__bf16)src[e];
    *(bf16x8*)(regA + row * 512 + ((cc ^ (row & 7)) << 4)) = v;
  }
  __syncthreads();

  // ============ A-phase: x -> h (8 x 128-wide sub) -> adp out ============
#pragma unroll 1
  for (int ch = 0; ch < 8; ++ch) {
    f32x4 acc1[4][2];
#pragma unroll
    for (int j = 0; j < 2; ++j) {
      const float bv = ba1[ch * 128 + wn * 32 + j * 16 + lr];
#pragma unroll
      for (int m = 0; m < 4; ++m) acc1[m][j] = {bv, bv, bv, bv};
    }
    // A1: h_sub = x @ wa1[:, ch*128:+128]   (K=256 from regA)
    mm_l2<8, 2, 9>(regA, pa1 + ((long)(ch * 8 + wn * 2) << 9) + (l << 3),
                   (long)64 << 9, row0, lr, lk, acc1);
    __syncthreads();  // prev A2 regB readers done
    store_gelu128(regB, acc1);
    __syncthreads();
    // A2: acc2 += h_sub @ wa2[ch*128:+128, :]   (K=128 from regB)
    mm_l2<4, 4, 8>(regB, pa2 + ((long)(ch * 64 + wn * 4) << 9) + (l << 3),
                   (long)16 << 9, row0, lr, lk, acc2);
  }

  // ---- LN1 in fragment layout -> regA bf16; stage motion -> regM ----
  {
    float mean[4][4], rstd[4][4];
    ln_stats(acc2, mean, rstd);  // internal sync: A2 done by all waves
#pragma unroll
    for (int j = 0; j < 4; ++j) {
      const int col = colb + j * 16 + lr;
      const float gv = ng[col], bv = nb[col];
#pragma unroll
      for (int m = 0; m < 4; ++m)
#pragma unroll
        for (int e = 0; e < 4; ++e) {
          const int row = row0 + m * 16 + lk * 4 + e;
          const float v = (acc2[m][j][e] - mean[m][e]) * rstd[m][e] * gv + bv;
          *(__bf16*)(regA + row * 512 + (((col >> 3) ^ (row & 7)) << 4) +
                     ((col & 7) << 1)) = (__bf16)v;
        }
    }
    {  // motion tile -> regM (dedicated region); 128x32 bf16
      const int row = tid >> 2, cc = tid & 3;
      const float* src = motion + (rowbase + row) * 32 + cc * 8;
      bf16x8 v;
#pragma unroll
      for (int e = 0; e < 8; ++e) v[e] = (__bf16)src[e];
      *(bf16x8*)(regM + row * 64 + ((cc ^ (row & 3)) << 4)) = v;
    }
  }
  __syncthreads();

  // ============ B-phase: fus MLP (2 x 128-wide hidden sub) ============
  {
    f32x4 accD[4][4];
#pragma unroll
    for (int j = 0; j < 4; ++j) {
      const float bv = bf2[colb + j * 16 + lr];
#pragma unroll
      for (int m = 0; m < 4; ++m) accD[m][j] = {bv, bv, bv, bv};
    }
#pragma unroll 1
    for (int n0 = 0; n0 < 2; ++n0) {
      f32x4 accB[4][2];
#pragma unroll
      for (int j = 0; j < 2; ++j) {
        const float bv = bf1[n0 * 128 + wn * 32 + j * 16 + lr];
#pragma unroll
        for (int m = 0; m < 4; ++m) accB[m][j] = {bv, bv, bv, bv};
      }
      // B1 main: LN1-out @ wf1[:256, sub]   (K=256 from regA)
      mm_l2<8, 2, 9>(regA, pf1 + ((long)(n0 * 8 + wn * 2) << 9) + (l << 3),
                     (long)16 << 9, row0, lr, lk, accB);
      {  // B1 motion: K=32 from regM (rows 256..287 of wf1)
        bf16x8 a[4];
#pragma unroll
        for (int m = 0; m < 4; ++m) {
          const int row = row0 + m * 16 + lr;
          a[m] = *(const bf16x8*)(regM + row * 64 + ((lk ^ (row & 3)) << 4));
        }
#pragma unroll
        for (int j = 0; j < 2; ++j) {
          const bf16x8 b = ldb(pf1, 128 + n0 * 8 + wn * 2 + j);
#pragma unroll
          for (int m = 0; m < 4; ++m)
            accB[m][j] = __builtin_amdgcn_mfma_f32_16x16x32_bf16(
                a[m], b, accB[m][j], 0, 0, 0);
        }
      }
      __syncthreads();           // prev-sub B2 regB readers done
      store_gelu128(regB, accB);  // g1 sub
      __syncthreads();
      // B2 partial: accD += g1_sub @ wf2[n0*128:+128, :]   (K=128 from regB)
      mm_l2<4, 4, 8>(regB, pf2 + ((long)(n0 * 64 + wn * 4) << 9) + (l << 3),
                     (long)16 << 9, row0, lr, lk, accD);
    }
    // tail: f -> regA (C1 input, bf16) ; acc2 = f + bn2
#pragma unroll
    for (int j = 0; j < 4; ++j) {
      const int col = colb + j * 16 + lr;
      const float bv = bn2[col];
#pragma unroll
      for (int m = 0; m < 4; ++m)
#pragma unroll
        for (int e = 0; e < 4; ++e) {
          const int row = row0 + m * 16 + lk * 4 + e;
          const float fv = accD[m][j][e];
          *(__bf16*)(regA + row * 512 + (((col >> 3) ^ (row & 7)) << 4) +
                     ((col & 7) << 1)) = (__bf16)fv;  // C1 input
          acc2[m][j][e] = fv + bv;  // residual + bias folded into C accum
        }
    }
  }
  __syncthreads();

  // ============ C-phase: ffn on f (8 x 128-wide sub) ============
#pragma unroll 1
  for (int ch = 0; ch < 8; ++ch) {
    f32x4 acc1[4][2];
#pragma unroll
    for (int j = 0; j < 2; ++j) {
      const float bv = bn1[ch * 128 + wn * 32 + j * 16 + lr];
#pragma unroll
      for (int m = 0; m < 4; ++m) acc1[m][j] = {bv, bv, bv, bv};
    }
    mm_l2<8, 2, 9>(regA, pn1 + ((long)(ch * 8 + wn * 2) << 9) + (l << 3),
                   (long)64 << 9, row0, lr, lk, acc1);
    __syncthreads();  // prev C2 regB readers done
    store_gelu128(regB, acc1);
    __syncthreads();
    mm_l2<4, 4, 8>(regB, pn2 + ((long)(ch * 64 + wn * 4) << 9) + (l << 3),
                   (long)16 << 9, row0, lr, lk, acc2);
  }

  // ---- LN2 in fragment layout -> global out ----
  {
    float mean[4][4], rstd[4][4];
    ln_stats(acc2, mean, rstd);
#pragma unroll
    for (int j = 0; j < 4; ++j) {
      const int col = colb + j * 16 + lr;
      const float gv = fg[col], bv = fb[col];
#pragma unroll
      for (int m = 0; m < 4; ++m)
#pragma unroll
        for (int e = 0; e < 4; ++e) {
          const int row = row0 + m * 16 + lk * 4 + e;
          out[(rowbase + row) * 256 + col] =
              (acc2[m][j][e] - mean[m][e]) * rstd[m][e] * gv + bv;
        }
    }
  }
}

}  // namespace

extern "C" void kernel_launch(void* const* d_in, const int* in_sizes, int n_in,
                              void* d_out, int out_size, void* d_ws, size_t ws_size,
                              hipStream_t stream) {
  const float* feats = (const float*)d_in[0];
  const float* boxes = (const float*)d_in[1];
  const void*  masks = d_in[2];
  const int*   times = (const int*)d_in[3];
  const float* wa1 = (const float*)d_in[4];
  const float* ba1 = (const float*)d_in[5];
  const float* wa2 = (const float*)d_in[6];
  const float* ba2 = (const float*)d_in[7];
  const float* ng  = (const float*)d_in[8];
  const float* nb  = (const float*)d_in[9];
  const float* mw1 = (const float*)d_in[10];
  const float* mb1 = (const float*)d_in[11];
  const float* mw2 = (const float*)d_in[12];
  const float* mb2 = (const float*)d_in[13];
  const float* wf1 = (const float*)d_in[14];
  const float* bf1 = (const float*)d_in[15];
  const float* wf2 = (const float*)d_in[16];
  const float* bf2 = (const float*)d_in[17];
  const float* wn1 = (const float*)d_in[18];
  const float* bn1 = (const float*)d_in[19];
  const float* wn2 = (const float*)d_in[20];
  const float* bn2 = (const float*)d_in[21];
  const float* fg  = (const float*)d_in[22];
  const float* fb  = (const float*)d_in[23];

  float* out_fused = (float*)d_out;
  float* out_motion = out_fused + FUSED_N;
  int* flag = (int*)d_ws;
  __bf16* pw = (__bf16*)((char*)d_ws + 256);

  const int mask_elems = in_sizes[2];  // 153600

  k_zero_flag<<<1, 1, 0, stream>>>(flag);
  k_detect_mask<<<(mask_elems + 255) / 256, 256, 0, stream>>>(
      (const unsigned char*)masks, mask_elems, flag);
  k_motion<<<(BG_ * N_) / 4, 256, 0, stream>>>(boxes, masks, times, mw1, mb1, mw2,
                                               mb2, out_motion, flag);

  auto packn = [&](const float* W, long off, int K, int NN) {
    const int total = (K / 32) * (NN / 16) * 64;
    k_pack<<<(total + 255) / 256, 256, 0, stream>>>(W, pw + off, K, NN);
  };
  packn(wa1, PA1, 256, 1024);
  packn(wa2, PA2, 1024, 256);
  packn(wf1, PF1, 288, 256);
  packn(wf2, PF2, 256, 256);
  packn(wn1, PN1, 256, 1024);
  packn(wn2, PN2, 1024, 256);

  k_mfma<<<(int)(MROWS_ / MB), 512, 0, stream>>>(
      feats, out_motion, pw, ba1, ba2, ng, nb, bf1, bf2, bn1, bn2, fg, fb,
      out_fused);
}